// Round 2
// baseline (2001.725 us; speedup 1.0000x reference)
//
#include <hip/hip_runtime.h>
#include <hip/hip_bf16.h>
#include <math.h>

// Problem constants
#define NTOK  131072   // B * H * W
#define NTOKH 65536    // tokens per batch image
#define CD    192
#define HID   768

__device__ __forceinline__ float bf2f(unsigned short v) {
    union { unsigned int u; float f; } c; c.u = ((unsigned int)v) << 16; return c.f;
}
__device__ __forceinline__ unsigned short f2bf(float f) {
    __hip_bfloat16 h = __float2bfloat16(f);
    return *reinterpret_cast<unsigned short*>(&h);
}
__device__ __forceinline__ float gelu_f(float x) {
    return 0.5f * x * (1.0f + erff(x * 0.7071067811865476f));
}

// ---------------- LayerNorm: one wave (64 lanes) per token, C=192=64*3; bf16 out ----------------
__global__ __launch_bounds__(256) void ln_kernel(const float* __restrict__ x,
                                                 const float* __restrict__ g,
                                                 const float* __restrict__ b,
                                                 unsigned short* __restrict__ out) {
    int tok  = blockIdx.x * 4 + (threadIdx.x >> 6);
    int lane = threadIdx.x & 63;
    const float* xp = x + (size_t)tok * CD;
    float v0 = xp[lane], v1 = xp[lane + 64], v2 = xp[lane + 128];
    float s  = v0 + v1 + v2;
    float s2 = v0 * v0 + v1 * v1 + v2 * v2;
    #pragma unroll
    for (int off = 32; off > 0; off >>= 1) {
        s  += __shfl_xor(s,  off, 64);
        s2 += __shfl_xor(s2, off, 64);
    }
    float mu  = s * (1.0f / 192.0f);
    float var = s2 * (1.0f / 192.0f) - mu * mu;
    float rs  = rsqrtf(var + 1e-5f);
    unsigned short* op = out + (size_t)tok * CD;
    op[lane]       = f2bf((v0 - mu) * rs * g[lane]       + b[lane]);
    op[lane + 64]  = f2bf((v1 - mu) * rs * g[lane + 64]  + b[lane + 64]);
    op[lane + 128] = f2bf((v2 - mu) * rs * g[lane + 128] + b[lane + 128]);
}

// ---------------- Tiled GEMM (A bf16, W fp32, fp32 accumulate) with fused epilogues ----------------
// MODE 0: QKV  W0=wq(192x192), W1=wkv(192x96); q=(acc+bq)*scale -> bf16 O0, kv=acc+bkv -> bf16 O1
// MODE 1: PROJ out(fp32 O0) = acc + b0 + addsrc
// MODE 2: FC1  out(bf16 O0) = gelu(acc + b0)
// MODE 3: FC2  out(fp32 O0) += acc + b0        (in-place accumulate into O0)
template<int MODE>
__global__ __launch_bounds__(256) void gemm_kernel(
    const unsigned short* __restrict__ A,
    const float* __restrict__ W0, const float* __restrict__ W1,
    const float* __restrict__ b0, const float* __restrict__ b1,
    const float* addsrc,
    void* O0, unsigned short* __restrict__ O1,
    int K, int N)
{
    constexpr int BM = 128, BN = 64, BK = 32;
    __shared__ float As[BK][BM + 4];   // stored transposed: As[k][m]
    __shared__ float Ws[BK][BN + 4];
    const int tid = threadIdx.x;
    const int m0 = blockIdx.y * BM;
    const int n0 = blockIdx.x * BN;

    float acc[8][4];
    #pragma unroll
    for (int i = 0; i < 8; i++)
        #pragma unroll
        for (int j = 0; j < 4; j++) acc[i][j] = 0.f;

    const int a_row = tid >> 3;        // 0..31
    const int a_k   = (tid & 7) * 4;   // 0..28
    const int w_n   = (tid & 15) * 4;  // 0..60
    const int w_k   = tid >> 4;        // 0..15
    const int tn    = (tid & 15) * 4;
    const int tm    = (tid >> 4) * 8;

    for (int k0 = 0; k0 < K; k0 += BK) {
        // stage A (128 x 32), bf16 -> fp32
        #pragma unroll
        for (int rr = 0; rr < 4; rr++) {
            int m = a_row + rr * 32;
            const unsigned short* Ab = A + (size_t)(m0 + m) * K + k0 + a_k;
            ushort4 u = *(const ushort4*)Ab;
            As[a_k + 0][m] = bf2f(u.x);
            As[a_k + 1][m] = bf2f(u.y);
            As[a_k + 2][m] = bf2f(u.z);
            As[a_k + 3][m] = bf2f(u.w);
        }
        // stage W (32 x 64)
        #pragma unroll
        for (int kk = 0; kk < 2; kk++) {
            int k = w_k + kk * 16;
            int n = n0 + w_n;
            float4 wv;
            if (MODE == 0) {
                if (n < 192)      wv = *(const float4*)(W0 + (size_t)(k0 + k) * 192 + n);
                else if (n < 288) wv = *(const float4*)(W1 + (size_t)(k0 + k) * 96 + (n - 192));
                else              wv = make_float4(0.f, 0.f, 0.f, 0.f);
            } else {
                wv = *(const float4*)(W0 + (size_t)(k0 + k) * N + n);
            }
            *(float4*)&Ws[k][w_n] = wv;
        }
        __syncthreads();

        #pragma unroll
        for (int k = 0; k < BK; k++) {
            float4 a0 = *(float4*)&As[k][tm];
            float4 a1 = *(float4*)&As[k][tm + 4];
            float4 wv = *(float4*)&Ws[k][tn];
            float am[8] = {a0.x, a0.y, a0.z, a0.w, a1.x, a1.y, a1.z, a1.w};
            float wn[4] = {wv.x, wv.y, wv.z, wv.w};
            #pragma unroll
            for (int i = 0; i < 8; i++)
                #pragma unroll
                for (int j = 0; j < 4; j++)
                    acc[i][j] = fmaf(am[i], wn[j], acc[i][j]);
        }
        __syncthreads();
    }

    #pragma unroll
    for (int i = 0; i < 8; i++) {
        size_t m = (size_t)(m0 + tm + i);
        #pragma unroll
        for (int j = 0; j < 4; j++) {
            int n = n0 + tn + j;
            float v = acc[i][j];
            if (MODE == 0) {
                if (n < 192)
                    ((unsigned short*)O0)[m * 192 + n] = f2bf((v + b0[n]) * 0.17677669529663687f);
                else if (n < 288)
                    O1[m * 96 + (n - 192)] = f2bf(v + b1[n - 192]);
            } else if (MODE == 1) {
                ((float*)O0)[m * (size_t)N + n] = v + b0[n] + addsrc[m * (size_t)N + n];
            } else if (MODE == 2) {
                ((unsigned short*)O0)[m * (size_t)N + n] = f2bf(gelu_f(v + b0[n]));
            } else { // MODE 3: in-place accumulate
                float* op = (float*)O0;
                size_t idx = m * (size_t)N + n;
                op[idx] = op[idx] + v + b0[n];
            }
        }
    }
}

// ---------------- PSA attention: 1 block per 8x8 window, thread = (head, q-token) ----------------
__global__ __launch_bounds__(384) void attn_kernel(
    const unsigned short* __restrict__ q, const unsigned short* __restrict__ kvp,
    const float* __restrict__ bt, unsigned short* __restrict__ aw)
{
    __shared__ float ks[6][16][32];
    __shared__ float vs[6][16][32];
    const int w = blockIdx.x;
    const int b = w >> 10, rem = w & 1023, wh = rem >> 5, wc = rem & 31;
    const int tid = threadIdx.x;
    const size_t base = (size_t)b * 65536;

    // load k/v with the PSA rearrange: kv token (d1,d3), head-flat f = d2*96 + d4*48 + c4
    for (int e = tid; e < 16 * 192; e += 384) {
        int kk = e / 192, f = e - kk * 192;
        int d1 = kk >> 2, d3 = kk & 3;
        int d2 = f / 96;  int r = f - d2 * 96;
        int d4 = r / 48;  int c4 = r - d4 * 48;
        int i = 2 * d1 + d2, j = 2 * d3 + d4;
        size_t g = base + (size_t)(wh * 8 + i) * 256 + (wc * 8 + j);
        int h = f >> 5, d = f & 31;
        ks[h][kk][d] = bf2f(kvp[g * 96 + c4]);
        vs[h][kk][d] = bf2f(kvp[g * 96 + 48 + c4]);
    }
    __syncthreads();

    const int t = tid & 63, h = tid >> 6;   // h uniform per wave
    const int i = t >> 3, j = t & 7;
    const int iq2 = i >> 1, jq2 = j >> 1;
    const size_t g = base + (size_t)(wh * 8 + i) * 256 + (wc * 8 + j);

    float qr[32];
    const ushort4* qp = (const ushort4*)(q + g * 192 + h * 32);
    #pragma unroll
    for (int d4i = 0; d4i < 8; d4i++) {
        ushort4 u = qp[d4i];
        qr[d4i * 4 + 0] = bf2f(u.x); qr[d4i * 4 + 1] = bf2f(u.y);
        qr[d4i * 4 + 2] = bf2f(u.z); qr[d4i * 4 + 3] = bf2f(u.w);
    }

    float lg[16]; float mx = -1e30f;
    #pragma unroll
    for (int kk = 0; kk < 16; kk++) {
        int kh = kk >> 2, kw = kk & 3;
        float s = bt[((iq2 - kh + 3) * 7 + (jq2 - kw + 3)) * 6 + h];
        #pragma unroll
        for (int d = 0; d < 32; d++) s = fmaf(qr[d], ks[h][kk][d], s);
        lg[kk] = s; mx = fmaxf(mx, s);
    }
    float den = 0.f;
    #pragma unroll
    for (int kk = 0; kk < 16; kk++) { lg[kk] = expf(lg[kk] - mx); den += lg[kk]; }
    float inv = 1.0f / den;

    float oacc[32];
    #pragma unroll
    for (int d = 0; d < 32; d++) oacc[d] = 0.f;
    #pragma unroll
    for (int kk = 0; kk < 16; kk++) {
        float p = lg[kk] * inv;
        #pragma unroll
        for (int d = 0; d < 32; d++) oacc[d] = fmaf(p, vs[h][kk][d], oacc[d]);
    }
    unsigned short* op = aw + g * 192 + h * 32;
    #pragma unroll
    for (int d = 0; d < 32; d++) op[d] = f2bf(oacc[d]);
}

// ---------------- Depthwise 5x5 conv + GELU + residual, one batch image (bf16 in/out) ----------------
__global__ __launch_bounds__(256) void dwconv_kernel(
    const unsigned short* __restrict__ h1,
    const float* __restrict__ dwk, const float* __restrict__ dwb,
    unsigned short* __restrict__ hout)
{
    __shared__ float tile[12][12][64];
    __shared__ float wts[64][25];
    __shared__ float bs[64];
    int bx = blockIdx.x;
    int chb = bx % 12; int t = bx / 12;
    int tw = t % 32; int th = t / 32;
    const int tid = threadIdx.x;
    const int chbase = chb * 64;

    for (int e = tid; e < 64 * 25; e += 256) {
        int ch = e / 25, tap = e - ch * 25;
        wts[ch][tap] = dwk[(size_t)(chbase + ch) * 25 + tap];
    }
    if (tid < 64) bs[tid] = dwb[chbase + tid];

    const int lane4 = tid & 15;
    const int pg = tid >> 4;
    for (int p = pg; p < 144; p += 16) {
        int pr = p / 12, pc = p - pr * 12;
        int r = th * 8 - 2 + pr, c = tw * 8 - 2 + pc;
        float f0 = 0.f, f1 = 0.f, f2 = 0.f, f3 = 0.f;
        if (r >= 0 && r < 256 && c >= 0 && c < 256) {
            const unsigned short* sp = h1 + (((size_t)r * 256 + c) * HID + chbase + lane4 * 4);
            ushort4 u = *(const ushort4*)sp;
            f0 = bf2f(u.x); f1 = bf2f(u.y); f2 = bf2f(u.z); f3 = bf2f(u.w);
        }
        tile[pr][pc][lane4 * 4 + 0] = f0;
        tile[pr][pc][lane4 * 4 + 1] = f1;
        tile[pr][pc][lane4 * 4 + 2] = f2;
        tile[pr][pc][lane4 * 4 + 3] = f3;
    }
    __syncthreads();

    const int ch = tid & 63;
    for (int pp = (tid >> 6); pp < 64; pp += 4) {
        int r0 = pp >> 3, c0 = pp & 7;
        float s = 0.f;
        #pragma unroll
        for (int kr = 0; kr < 5; kr++)
            #pragma unroll
            for (int kc = 0; kc < 5; kc++)
                s = fmaf(tile[r0 + kr][c0 + kc][ch], wts[ch][kr * 5 + kc], s);
        float center = tile[r0 + 2][c0 + 2][ch];
        float res = center + gelu_f(s + bs[ch]);
        size_t tok = (size_t)(th * 8 + r0) * 256 + (tw * 8 + c0);
        hout[tok * HID + chbase + ch] = f2bf(res);
    }
}

// ---------------- launch ----------------
extern "C" void kernel_launch(void* const* d_in, const int* in_sizes, int n_in,
                              void* d_out, int out_size, void* d_ws, size_t ws_size,
                              hipStream_t stream) {
    const float* x    = (const float*)d_in[0];
    const float* g1   = (const float*)d_in[1];
    const float* be1  = (const float*)d_in[2];
    const float* wq   = (const float*)d_in[3];
    const float* bq   = (const float*)d_in[4];
    const float* wkv  = (const float*)d_in[5];
    const float* bkv  = (const float*)d_in[6];
    const float* btab = (const float*)d_in[7];
    const float* wproj= (const float*)d_in[8];
    const float* bproj= (const float*)d_in[9];
    const float* g2   = (const float*)d_in[10];
    const float* be2  = (const float*)d_in[11];
    const float* w1f  = (const float*)d_in[12];
    const float* b1f  = (const float*)d_in[13];
    const float* dwk  = (const float*)d_in[14];
    const float* dwb  = (const float*)d_in[15];
    const float* w2f  = (const float*)d_in[16];
    const float* b2f  = (const float*)d_in[17];
    float* out = (float*)d_out;

    // workspace layout (bytes), peak 327.2 MB:
    //   [xnb/awb bf16 50.3][qb/xn2b bf16 50.3][kvb bf16 25.2][h1 half bf16 100.7][h half bf16 100.7]
    char* ws = (char*)d_ws;
    unsigned short* xnb = (unsigned short*)(ws);              // xn -> aw (bf16)
    unsigned short* qb  = (unsigned short*)(ws + 50331648);   // q  -> xn2 (bf16)
    unsigned short* kvb = (unsigned short*)(ws + 100663296);  // kv (bf16)
    unsigned short* h1b = (unsigned short*)(ws + 125829120);  // h1, one image (bf16)
    unsigned short* hhb = (unsigned short*)(ws + 226492416);  // h,  one image (bf16)

    // 1) LN1 -> xnb
    ln_kernel<<<NTOK / 4, 256, 0, stream>>>(x, g1, be1, xnb);
    // 2) QKV projection (N=288: 5 tiles of 64) -> qb, kvb
    gemm_kernel<0><<<dim3(5, NTOK / 128), 256, 0, stream>>>(
        xnb, wq, wkv, bq, bkv, nullptr, qb, kvb, 192, 288);
    // 3) attention -> aw (token-major => window_reverse identity), overlays xnb
    attn_kernel<<<2048, 384, 0, stream>>>(qb, kvb, btab, xnb);
    // 4) proj + residual -> xattn lives in d_out
    gemm_kernel<1><<<dim3(3, NTOK / 128), 256, 0, stream>>>(
        xnb, wproj, nullptr, bproj, nullptr, x, out, nullptr, 192, 192);
    // 5) LN2 -> xn2b (overlays qb)
    ln_kernel<<<NTOK / 4, 256, 0, stream>>>(out, g2, be2, qb);
    // 6-8) ConvFFN per batch image; FC2 accumulates into d_out (xattn already there)
    for (int half = 0; half < 2; half++) {
        const unsigned short* xn2h = qb + (size_t)half * NTOKH * CD;
        float* outh = out + (size_t)half * NTOKH * CD;
        gemm_kernel<2><<<dim3(12, NTOKH / 128), 256, 0, stream>>>(
            xn2h, w1f, nullptr, b1f, nullptr, nullptr, h1b, nullptr, 192, 768);
        dwconv_kernel<<<12 * 32 * 32, 256, 0, stream>>>(h1b, dwk, dwb, hhb);
        gemm_kernel<3><<<dim3(3, NTOKH / 128), 256, 0, stream>>>(
            hhb, w2f, nullptr, b2f, nullptr, nullptr, outh, nullptr, 768, 192);
    }
}

// Round 3
// 1038.513 us; speedup vs baseline: 1.9275x; 1.9275x over previous
//
#include <hip/hip_runtime.h>
#include <hip/hip_bf16.h>
#include <math.h>

// Problem constants
#define NTOK  131072   // B * H * W
#define NTOKH 65536    // tokens per batch image
#define CD    192
#define HID   768

typedef short bf16x8 __attribute__((ext_vector_type(8)));
typedef float f32x4  __attribute__((ext_vector_type(4)));

__device__ __forceinline__ float bf2f(unsigned short v) {
    union { unsigned int u; float f; } c; c.u = ((unsigned int)v) << 16; return c.f;
}
__device__ __forceinline__ unsigned short f2bf(float f) {
    __hip_bfloat16 h = __float2bfloat16(f);
    return *reinterpret_cast<unsigned short*>(&h);
}
__device__ __forceinline__ float gelu_f(float x) {
    return 0.5f * x * (1.0f + erff(x * 0.7071067811865476f));
}

// ---------------- LayerNorm: one wave per token, C=192=64*3; bf16 out ----------------
__global__ __launch_bounds__(256) void ln_kernel(const float* __restrict__ x,
                                                 const float* __restrict__ g,
                                                 const float* __restrict__ b,
                                                 unsigned short* __restrict__ out) {
    int tok  = blockIdx.x * 4 + (threadIdx.x >> 6);
    int lane = threadIdx.x & 63;
    const float* xp = x + (size_t)tok * CD;
    float v0 = xp[lane], v1 = xp[lane + 64], v2 = xp[lane + 128];
    float s  = v0 + v1 + v2;
    float s2 = v0 * v0 + v1 * v1 + v2 * v2;
    #pragma unroll
    for (int off = 32; off > 0; off >>= 1) {
        s  += __shfl_xor(s,  off, 64);
        s2 += __shfl_xor(s2, off, 64);
    }
    float mu  = s * (1.0f / 192.0f);
    float var = s2 * (1.0f / 192.0f) - mu * mu;
    float rs  = rsqrtf(var + 1e-5f);
    unsigned short* op = out + (size_t)tok * CD;
    op[lane]       = f2bf((v0 - mu) * rs * g[lane]       + b[lane]);
    op[lane + 64]  = f2bf((v1 - mu) * rs * g[lane + 64]  + b[lane + 64]);
    op[lane + 128] = f2bf((v2 - mu) * rs * g[lane + 128] + b[lane + 128]);
}

// ---------------- weight transpose+cast pre-pass (tiny: 0.39M elems) ----------------
__global__ __launch_bounds__(256) void wconv_kernel(
    const float* __restrict__ wq, const float* __restrict__ wkv,
    const float* __restrict__ wproj, const float* __restrict__ w1f,
    const float* __restrict__ w2f,
    unsigned short* __restrict__ qkvT, unsigned short* __restrict__ projT,
    unsigned short* __restrict__ w1T, unsigned short* __restrict__ w2T)
{
    int i = blockIdx.x * 256 + threadIdx.x;   // 0 .. 147455
    if (i < 288 * 192) {
        int n = i / 192, k = i - n * 192;
        float v = (n < 192) ? wq[(size_t)k * 192 + n] : wkv[(size_t)k * 96 + (n - 192)];
        qkvT[n * 192 + k] = f2bf(v);
    }
    if (i < 192 * 192) {
        int n = i / 192, k = i - n * 192;
        projT[n * 192 + k] = f2bf(wproj[(size_t)k * 192 + n]);
    }
    {   // w1T: [768][192]
        int n = i / 192, k = i - n * 192;
        w1T[n * 192 + k] = f2bf(w1f[(size_t)k * 768 + n]);
    }
    {   // w2T: [192][768]
        int n = i / 768, k = i - n * 768;
        w2T[n * 768 + k] = f2bf(w2f[(size_t)k * 192 + n]);
    }
}

// ---------------- MFMA bf16 GEMM, 128x64 block tile, 4 waves 2x2, BK=32 ----------------
// MODE 0: QKV  q=(acc+b0)*scale -> bf16 O0 [m*192+n], kv=acc+b1 -> bf16 O1 [m*96+n-192]
// MODE 1: PROJ fp32 O0[m*192+n] = acc + b0[n] + addsrc[m*192+n]
// MODE 2: FC1  bf16 O0[m*768+n] = gelu(acc + b0[n])
// MODE 3: FC2  fp32 O0[m*192+n] += acc + b0[n]
template<int MODE>
__global__ __launch_bounds__(256) void mgemm_kernel(
    const unsigned short* __restrict__ A,    // [M][K] bf16
    const unsigned short* __restrict__ WT,   // [Nreal][K] bf16
    const float* __restrict__ b0, const float* __restrict__ b1,
    const float* __restrict__ addsrc,
    void* O0, unsigned short* __restrict__ O1,
    int K, int Nreal)
{
    constexpr int BM = 128, BN = 64, BK = 32;
    constexpr int LDA = BK + 8;   // 40 shorts = 80 B row stride (16B aligned, bank-spread)
    __shared__ unsigned short As[BM * LDA];
    __shared__ unsigned short Bs[BN * LDA];
    const int tid  = threadIdx.x;
    const int wave = tid >> 6, lane = tid & 63;
    const int quad = lane >> 4, l16 = lane & 15;
    const int wm = (wave >> 1) * 64, wn = (wave & 1) * 32;
    const int m0 = blockIdx.y * BM, n0 = blockIdx.x * BN;

    f32x4 acc[4][2];
    #pragma unroll
    for (int mi = 0; mi < 4; mi++)
        #pragma unroll
        for (int ni = 0; ni < 2; ni++) acc[mi][ni] = (f32x4){0.f, 0.f, 0.f, 0.f};

    const int sr = tid >> 2;         // 0..63
    const int sk = (tid & 3) * 8;    // 0,8,16,24

    for (int k0 = 0; k0 < K; k0 += BK) {
        // stage A: 128 rows x 32 k (two rows per thread), 16B vector loads
        #pragma unroll
        for (int rr = 0; rr < 2; rr++) {
            int m = sr + rr * 64;
            *(uint4*)&As[m * LDA + sk] =
                *(const uint4*)(A + (size_t)(m0 + m) * K + k0 + sk);
        }
        // stage WT: 64 rows x 32 k (one row per thread)
        {
            uint4 wv = make_uint4(0u, 0u, 0u, 0u);
            if (n0 + sr < Nreal)
                wv = *(const uint4*)(WT + (size_t)(n0 + sr) * K + k0 + sk);
            *(uint4*)&Bs[sr * LDA + sk] = wv;
        }
        __syncthreads();

        bf16x8 bf[2];
        #pragma unroll
        for (int ni = 0; ni < 2; ni++)
            bf[ni] = *(const bf16x8*)&Bs[(wn + ni * 16 + l16) * LDA + quad * 8];
        #pragma unroll
        for (int mi = 0; mi < 4; mi++) {
            bf16x8 af = *(const bf16x8*)&As[(wm + mi * 16 + l16) * LDA + quad * 8];
            acc[mi][0] = __builtin_amdgcn_mfma_f32_16x16x32_bf16(af, bf[0], acc[mi][0], 0, 0, 0);
            acc[mi][1] = __builtin_amdgcn_mfma_f32_16x16x32_bf16(af, bf[1], acc[mi][1], 0, 0, 0);
        }
        __syncthreads();
    }

    // epilogue: C/D layout col=lane&15, row=quad*4+reg
    #pragma unroll
    for (int mi = 0; mi < 4; mi++) {
        int row0 = m0 + wm + mi * 16 + quad * 4;
        #pragma unroll
        for (int ni = 0; ni < 2; ni++) {
            int col = n0 + wn + ni * 16 + l16;
            #pragma unroll
            for (int r = 0; r < 4; r++) {
                size_t m = (size_t)(row0 + r);
                float v = acc[mi][ni][r];
                if (MODE == 0) {
                    if (col < 192)
                        ((unsigned short*)O0)[m * 192 + col] =
                            f2bf((v + b0[col]) * 0.17677669529663687f);
                    else if (col < 288)
                        O1[m * 96 + (col - 192)] = f2bf(v + b1[col - 192]);
                } else if (MODE == 1) {
                    ((float*)O0)[m * 192 + col] = v + b0[col] + addsrc[m * 192 + col];
                } else if (MODE == 2) {
                    ((unsigned short*)O0)[m * 768 + col] = f2bf(gelu_f(v + b0[col]));
                } else {
                    float* op = (float*)O0;
                    op[m * 192 + col] = op[m * 192 + col] + v + b0[col];
                }
            }
        }
    }
}

// ---------------- PSA attention: 1 block per 8x8 window, thread = (head, q-token) ----------------
__global__ __launch_bounds__(384) void attn_kernel(
    const unsigned short* __restrict__ q, const unsigned short* __restrict__ kvp,
    const float* __restrict__ bt, unsigned short* __restrict__ aw)
{
    __shared__ float ks[6][16][32];
    __shared__ float vs[6][16][32];
    const int w = blockIdx.x;
    const int b = w >> 10, rem = w & 1023, wh = rem >> 5, wc = rem & 31;
    const int tid = threadIdx.x;
    const size_t base = (size_t)b * 65536;

    for (int e = tid; e < 16 * 192; e += 384) {
        int kk = e / 192, f = e - kk * 192;
        int d1 = kk >> 2, d3 = kk & 3;
        int d2 = f / 96;  int r = f - d2 * 96;
        int d4 = r / 48;  int c4 = r - d4 * 48;
        int i = 2 * d1 + d2, j = 2 * d3 + d4;
        size_t g = base + (size_t)(wh * 8 + i) * 256 + (wc * 8 + j);
        int h = f >> 5, d = f & 31;
        ks[h][kk][d] = bf2f(kvp[g * 96 + c4]);
        vs[h][kk][d] = bf2f(kvp[g * 96 + 48 + c4]);
    }
    __syncthreads();

    const int t = tid & 63, h = tid >> 6;
    const int i = t >> 3, j = t & 7;
    const int iq2 = i >> 1, jq2 = j >> 1;
    const size_t g = base + (size_t)(wh * 8 + i) * 256 + (wc * 8 + j);

    float qr[32];
    const ushort4* qp = (const ushort4*)(q + g * 192 + h * 32);
    #pragma unroll
    for (int d4i = 0; d4i < 8; d4i++) {
        ushort4 u = qp[d4i];
        qr[d4i * 4 + 0] = bf2f(u.x); qr[d4i * 4 + 1] = bf2f(u.y);
        qr[d4i * 4 + 2] = bf2f(u.z); qr[d4i * 4 + 3] = bf2f(u.w);
    }

    float lg[16]; float mx = -1e30f;
    #pragma unroll
    for (int kk = 0; kk < 16; kk++) {
        int kh = kk >> 2, kw = kk & 3;
        float s = bt[((iq2 - kh + 3) * 7 + (jq2 - kw + 3)) * 6 + h];
        #pragma unroll
        for (int d = 0; d < 32; d++) s = fmaf(qr[d], ks[h][kk][d], s);
        lg[kk] = s; mx = fmaxf(mx, s);
    }
    float den = 0.f;
    #pragma unroll
    for (int kk = 0; kk < 16; kk++) { lg[kk] = expf(lg[kk] - mx); den += lg[kk]; }
    float inv = 1.0f / den;

    float oacc[32];
    #pragma unroll
    for (int d = 0; d < 32; d++) oacc[d] = 0.f;
    #pragma unroll
    for (int kk = 0; kk < 16; kk++) {
        float p = lg[kk] * inv;
        #pragma unroll
        for (int d = 0; d < 32; d++) oacc[d] = fmaf(p, vs[h][kk][d], oacc[d]);
    }
    unsigned short* op = aw + g * 192 + h * 32;
    #pragma unroll
    for (int d = 0; d < 32; d++) op[d] = f2bf(oacc[d]);
}

// ---------------- Depthwise 5x5 conv + GELU + residual, one batch image ----------------
__global__ __launch_bounds__(256) void dwconv_kernel(
    const unsigned short* __restrict__ h1,
    const float* __restrict__ dwk, const float* __restrict__ dwb,
    unsigned short* __restrict__ hout)
{
    __shared__ float tile[12][12][64];
    __shared__ float wts[64][25];
    __shared__ float bs[64];
    int bx = blockIdx.x;
    int chb = bx % 12; int t = bx / 12;
    int tw = t % 32; int th = t / 32;
    const int tid = threadIdx.x;
    const int chbase = chb * 64;

    for (int e = tid; e < 64 * 25; e += 256) {
        int ch = e / 25, tap = e - ch * 25;
        wts[ch][tap] = dwk[(size_t)(chbase + ch) * 25 + tap];
    }
    if (tid < 64) bs[tid] = dwb[chbase + tid];

    const int lane4 = tid & 15;
    const int pg = tid >> 4;
    for (int p = pg; p < 144; p += 16) {
        int pr = p / 12, pc = p - pr * 12;
        int r = th * 8 - 2 + pr, c = tw * 8 - 2 + pc;
        float f0 = 0.f, f1 = 0.f, f2 = 0.f, f3 = 0.f;
        if (r >= 0 && r < 256 && c >= 0 && c < 256) {
            const unsigned short* sp = h1 + (((size_t)r * 256 + c) * HID + chbase + lane4 * 4);
            ushort4 u = *(const ushort4*)sp;
            f0 = bf2f(u.x); f1 = bf2f(u.y); f2 = bf2f(u.z); f3 = bf2f(u.w);
        }
        tile[pr][pc][lane4 * 4 + 0] = f0;
        tile[pr][pc][lane4 * 4 + 1] = f1;
        tile[pr][pc][lane4 * 4 + 2] = f2;
        tile[pr][pc][lane4 * 4 + 3] = f3;
    }
    __syncthreads();

    const int ch = tid & 63;
    for (int pp = (tid >> 6); pp < 64; pp += 4) {
        int r0 = pp >> 3, c0 = pp & 7;
        float s = 0.f;
        #pragma unroll
        for (int kr = 0; kr < 5; kr++)
            #pragma unroll
            for (int kc = 0; kc < 5; kc++)
                s = fmaf(tile[r0 + kr][c0 + kc][ch], wts[ch][kr * 5 + kc], s);
        float center = tile[r0 + 2][c0 + 2][ch];
        float res = center + gelu_f(s + bs[ch]);
        size_t tok = (size_t)(th * 8 + r0) * 256 + (tw * 8 + c0);
        hout[tok * HID + chbase + ch] = f2bf(res);
    }
}

// ---------------- launch ----------------
extern "C" void kernel_launch(void* const* d_in, const int* in_sizes, int n_in,
                              void* d_out, int out_size, void* d_ws, size_t ws_size,
                              hipStream_t stream) {
    const float* x    = (const float*)d_in[0];
    const float* g1   = (const float*)d_in[1];
    const float* be1  = (const float*)d_in[2];
    const float* wq   = (const float*)d_in[3];
    const float* bq   = (const float*)d_in[4];
    const float* wkv  = (const float*)d_in[5];
    const float* bkv  = (const float*)d_in[6];
    const float* btab = (const float*)d_in[7];
    const float* wproj= (const float*)d_in[8];
    const float* bproj= (const float*)d_in[9];
    const float* g2   = (const float*)d_in[10];
    const float* be2  = (const float*)d_in[11];
    const float* w1f  = (const float*)d_in[12];
    const float* b1f  = (const float*)d_in[13];
    const float* dwk  = (const float*)d_in[14];
    const float* dwb  = (const float*)d_in[15];
    const float* w2f  = (const float*)d_in[16];
    const float* b2f  = (const float*)d_in[17];
    float* out = (float*)d_out;

    // workspace layout (bytes), peak ~327.9 MB (known-safe: 327.2 passed, 528 faulted)
    char* ws = (char*)d_ws;
    unsigned short* xnb  = (unsigned short*)(ws);              // xn -> aw (bf16)
    unsigned short* qb   = (unsigned short*)(ws + 50331648);   // q  -> xn2 (bf16)
    unsigned short* kvb  = (unsigned short*)(ws + 100663296);  // kv (bf16)
    unsigned short* h1b  = (unsigned short*)(ws + 125829120);  // h1, one image (bf16)
    unsigned short* hhb  = (unsigned short*)(ws + 226492416);  // h,  one image (bf16)
    unsigned short* qkvT = (unsigned short*)(ws + 327155712);  // [288][192]
    unsigned short* projT= (unsigned short*)(ws + 327266304);  // [192][192]
    unsigned short* w1T  = (unsigned short*)(ws + 327340032);  // [768][192]
    unsigned short* w2T  = (unsigned short*)(ws + 327634944);  // [192][768]

    // 0) weight transpose+cast (0.39M elems)
    wconv_kernel<<<576, 256, 0, stream>>>(wq, wkv, wproj, w1f, w2f,
                                          qkvT, projT, w1T, w2T);
    // 1) LN1 -> xnb
    ln_kernel<<<NTOK / 4, 256, 0, stream>>>(x, g1, be1, xnb);
    // 2) QKV projection -> qb, kvb   (Nreal=288, 5 tiles of 64)
    mgemm_kernel<0><<<dim3(5, NTOK / 128), 256, 0, stream>>>(
        xnb, qkvT, bq, bkv, nullptr, qb, kvb, 192, 288);
    // 3) attention -> aw (token-major), overlays xnb
    attn_kernel<<<2048, 384, 0, stream>>>(qb, kvb, btab, xnb);
    // 4) proj + residual -> xattn lives in d_out
    mgemm_kernel<1><<<dim3(3, NTOK / 128), 256, 0, stream>>>(
        xnb, projT, bproj, nullptr, x, out, nullptr, 192, 192);
    // 5) LN2 -> xn2b (overlays qb)
    ln_kernel<<<NTOK / 4, 256, 0, stream>>>(out, g2, be2, qb);
    // 6-8) ConvFFN per batch image; FC2 accumulates into d_out
    for (int half = 0; half < 2; half++) {
        const unsigned short* xn2h = qb + (size_t)half * NTOKH * CD;
        float* outh = out + (size_t)half * NTOKH * CD;
        mgemm_kernel<2><<<dim3(12, NTOKH / 128), 256, 0, stream>>>(
            xn2h, w1T, b1f, nullptr, nullptr, h1b, nullptr, 192, 768);
        dwconv_kernel<<<12 * 32 * 32, 256, 0, stream>>>(h1b, dwk, dwb, hhb);
        mgemm_kernel<3><<<dim3(3, NTOKH / 128), 256, 0, stream>>>(
            hhb, w2T, b2f, nullptr, nullptr, outh, nullptr, 768, 192);
    }
}

// Round 4
// 906.869 us; speedup vs baseline: 2.2073x; 1.1452x over previous
//
#include <hip/hip_runtime.h>
#include <hip/hip_bf16.h>
#include <math.h>

// Problem constants
#define NTOK  131072   // B * H * W
#define NTOKH 65536    // tokens per batch image
#define CD    192
#define HID   768

typedef short bf16x8 __attribute__((ext_vector_type(8)));
typedef float f32x4  __attribute__((ext_vector_type(4)));

__device__ __forceinline__ float bf2f(unsigned short v) {
    union { unsigned int u; float f; } c; c.u = ((unsigned int)v) << 16; return c.f;
}
__device__ __forceinline__ unsigned short f2bf(float f) {
    __hip_bfloat16 h = __float2bfloat16(f);
    return *reinterpret_cast<unsigned short*>(&h);
}
__device__ __forceinline__ float gelu_f(float x) {
    return 0.5f * x * (1.0f + erff(x * 0.7071067811865476f));
}

// ---------------- LayerNorm: one wave per token, C=192=64*3; bf16 out ----------------
__global__ __launch_bounds__(256) void ln_kernel(const float* __restrict__ x,
                                                 const float* __restrict__ g,
                                                 const float* __restrict__ b,
                                                 unsigned short* __restrict__ out) {
    int tok  = blockIdx.x * 4 + (threadIdx.x >> 6);
    int lane = threadIdx.x & 63;
    const float* xp = x + (size_t)tok * CD;
    float v0 = xp[lane], v1 = xp[lane + 64], v2 = xp[lane + 128];
    float s  = v0 + v1 + v2;
    float s2 = v0 * v0 + v1 * v1 + v2 * v2;
    #pragma unroll
    for (int off = 32; off > 0; off >>= 1) {
        s  += __shfl_xor(s,  off, 64);
        s2 += __shfl_xor(s2, off, 64);
    }
    float mu  = s * (1.0f / 192.0f);
    float var = s2 * (1.0f / 192.0f) - mu * mu;
    float rs  = rsqrtf(var + 1e-5f);
    unsigned short* op = out + (size_t)tok * CD;
    op[lane]       = f2bf((v0 - mu) * rs * g[lane]       + b[lane]);
    op[lane + 64]  = f2bf((v1 - mu) * rs * g[lane + 64]  + b[lane + 64]);
    op[lane + 128] = f2bf((v2 - mu) * rs * g[lane + 128] + b[lane + 128]);
}

// ---------------- weight transpose+cast pre-pass (tiny: 0.39M elems) ----------------
__global__ __launch_bounds__(256) void wconv_kernel(
    const float* __restrict__ wq, const float* __restrict__ wkv,
    const float* __restrict__ wproj, const float* __restrict__ w1f,
    const float* __restrict__ w2f,
    unsigned short* __restrict__ qkvT, unsigned short* __restrict__ projT,
    unsigned short* __restrict__ w1T, unsigned short* __restrict__ w2T)
{
    int i = blockIdx.x * 256 + threadIdx.x;   // 0 .. 147455
    if (i < 288 * 192) {
        int n = i / 192, k = i - n * 192;
        float v = (n < 192) ? wq[(size_t)k * 192 + n] : wkv[(size_t)k * 96 + (n - 192)];
        qkvT[n * 192 + k] = f2bf(v);
    }
    if (i < 192 * 192) {
        int n = i / 192, k = i - n * 192;
        projT[n * 192 + k] = f2bf(wproj[(size_t)k * 192 + n]);
    }
    {   // w1T: [768][192]
        int n = i / 192, k = i - n * 192;
        w1T[n * 192 + k] = f2bf(w1f[(size_t)k * 768 + n]);
    }
    {   // w2T: [192][768]
        int n = i / 768, k = i - n * 768;
        w2T[n * 768 + k] = f2bf(w2f[(size_t)k * 192 + n]);
    }
}

// ---------------- MFMA bf16 GEMM, 128x64 block tile, 4 waves 2x2, BK=64 ----------------
// MODE 0: QKV  q=(acc+b0)*scale -> bf16 O0 [m*192+n], kv=acc+b1 -> bf16 O1 [m*96+n-192]
// MODE 1: PROJ fp32 O0[m*192+n] = acc + b0[n] + addsrc[m*192+n]
// MODE 2: FC1  bf16 O0[m*768+n] = gelu(acc + b0[n])
// MODE 3: FC2  fp32 O0[m*192+n] += acc + b0[n]
template<int MODE>
__global__ __launch_bounds__(256) void mgemm_kernel(
    const unsigned short* __restrict__ A,    // [M][K] bf16
    const unsigned short* __restrict__ WT,   // [Nreal][K] bf16
    const float* __restrict__ b0, const float* __restrict__ b1,
    const float* __restrict__ addsrc,
    void* O0, unsigned short* __restrict__ O1,
    int K, int Nreal)
{
    constexpr int BM = 128, BN = 64, BK = 64;
    constexpr int LDA = BK + 8;   // 72 shorts = 144 B row stride (16B aligned)
    __shared__ unsigned short As[BM * LDA];
    __shared__ unsigned short Bs[BN * LDA];
    const int tid  = threadIdx.x;
    const int wave = tid >> 6, lane = tid & 63;
    const int quad = lane >> 4, l16 = lane & 15;
    const int wm = (wave >> 1) * 64, wn = (wave & 1) * 32;
    const int m0 = blockIdx.y * BM, n0 = blockIdx.x * BN;

    f32x4 acc[4][2];
    #pragma unroll
    for (int mi = 0; mi < 4; mi++)
        #pragma unroll
        for (int ni = 0; ni < 2; ni++) acc[mi][ni] = (f32x4){0.f, 0.f, 0.f, 0.f};

    const int ar  = tid >> 1;          // 0..127
    const int ak  = (tid & 1) * 32;    // 0 or 32 shorts
    const int br  = tid >> 2;          // 0..63
    const int bk  = (tid & 3) * 16;    // 0,16,32,48 shorts

    for (int k0 = 0; k0 < K; k0 += BK) {
        // stage A: 128 rows x 64 k; each thread 4 x 16B
        #pragma unroll
        for (int c = 0; c < 4; c++)
            *(uint4*)&As[ar * LDA + ak + c * 8] =
                *(const uint4*)(A + (size_t)(m0 + ar) * K + k0 + ak + c * 8);
        // stage WT: 64 rows x 64 k; each thread 2 x 16B
        #pragma unroll
        for (int c = 0; c < 2; c++) {
            uint4 wv = make_uint4(0u, 0u, 0u, 0u);
            if (n0 + br < Nreal)
                wv = *(const uint4*)(WT + (size_t)(n0 + br) * K + k0 + bk + c * 8);
            *(uint4*)&Bs[br * LDA + bk + c * 8] = wv;
        }
        __syncthreads();

        #pragma unroll
        for (int kk = 0; kk < 2; kk++) {
            bf16x8 bf[2];
            #pragma unroll
            for (int ni = 0; ni < 2; ni++)
                bf[ni] = *(const bf16x8*)&Bs[(wn + ni * 16 + l16) * LDA + kk * 32 + quad * 8];
            #pragma unroll
            for (int mi = 0; mi < 4; mi++) {
                bf16x8 af = *(const bf16x8*)&As[(wm + mi * 16 + l16) * LDA + kk * 32 + quad * 8];
                acc[mi][0] = __builtin_amdgcn_mfma_f32_16x16x32_bf16(af, bf[0], acc[mi][0], 0, 0, 0);
                acc[mi][1] = __builtin_amdgcn_mfma_f32_16x16x32_bf16(af, bf[1], acc[mi][1], 0, 0, 0);
            }
        }
        __syncthreads();
    }

    // epilogue: C/D layout col=lane&15, row=quad*4+reg
    #pragma unroll
    for (int mi = 0; mi < 4; mi++) {
        int row0 = m0 + wm + mi * 16 + quad * 4;
        #pragma unroll
        for (int ni = 0; ni < 2; ni++) {
            int col = n0 + wn + ni * 16 + l16;
            #pragma unroll
            for (int r = 0; r < 4; r++) {
                size_t m = (size_t)(row0 + r);
                float v = acc[mi][ni][r];
                if (MODE == 0) {
                    if (col < 192)
                        ((unsigned short*)O0)[m * 192 + col] =
                            f2bf((v + b0[col]) * 0.17677669529663687f);
                    else if (col < 288)
                        O1[m * 96 + (col - 192)] = f2bf(v + b1[col - 192]);
                } else if (MODE == 1) {
                    ((float*)O0)[m * 192 + col] = v + b0[col] + addsrc[m * 192 + col];
                } else if (MODE == 2) {
                    ((unsigned short*)O0)[m * 768 + col] = f2bf(gelu_f(v + b0[col]));
                } else {
                    float* op = (float*)O0;
                    op[m * 192 + col] = op[m * 192 + col] + v + b0[col];
                }
            }
        }
    }
}

// ---------------- PSA attention: 1 block per 8x8 window, thread = (head, q-token) ----------------
__global__ __launch_bounds__(384) void attn_kernel(
    const unsigned short* __restrict__ q, const unsigned short* __restrict__ kvp,
    const float* __restrict__ bt, unsigned short* __restrict__ aw)
{
    __shared__ float ks[6][16][32];
    __shared__ float vs[6][16][32];
    const int w = blockIdx.x;
    const int b = w >> 10, rem = w & 1023, wh = rem >> 5, wc = rem & 31;
    const int tid = threadIdx.x;
    const size_t base = (size_t)b * 65536;

    for (int e = tid; e < 16 * 192; e += 384) {
        int kk = e / 192, f = e - kk * 192;
        int d1 = kk >> 2, d3 = kk & 3;
        int d2 = f / 96;  int r = f - d2 * 96;
        int d4 = r / 48;  int c4 = r - d4 * 48;
        int i = 2 * d1 + d2, j = 2 * d3 + d4;
        size_t g = base + (size_t)(wh * 8 + i) * 256 + (wc * 8 + j);
        int h = f >> 5, d = f & 31;
        ks[h][kk][d] = bf2f(kvp[g * 96 + c4]);
        vs[h][kk][d] = bf2f(kvp[g * 96 + 48 + c4]);
    }
    __syncthreads();

    const int t = tid & 63, h = tid >> 6;
    const int i = t >> 3, j = t & 7;
    const int iq2 = i >> 1, jq2 = j >> 1;
    const size_t g = base + (size_t)(wh * 8 + i) * 256 + (wc * 8 + j);

    float qr[32];
    const ushort4* qp = (const ushort4*)(q + g * 192 + h * 32);
    #pragma unroll
    for (int d4i = 0; d4i < 8; d4i++) {
        ushort4 u = qp[d4i];
        qr[d4i * 4 + 0] = bf2f(u.x); qr[d4i * 4 + 1] = bf2f(u.y);
        qr[d4i * 4 + 2] = bf2f(u.z); qr[d4i * 4 + 3] = bf2f(u.w);
    }

    float lg[16]; float mx = -1e30f;
    #pragma unroll
    for (int kk = 0; kk < 16; kk++) {
        int kh = kk >> 2, kw = kk & 3;
        float s = bt[((iq2 - kh + 3) * 7 + (jq2 - kw + 3)) * 6 + h];
        #pragma unroll
        for (int d = 0; d < 32; d++) s = fmaf(qr[d], ks[h][kk][d], s);
        lg[kk] = s; mx = fmaxf(mx, s);
    }
    float den = 0.f;
    #pragma unroll
    for (int kk = 0; kk < 16; kk++) { lg[kk] = expf(lg[kk] - mx); den += lg[kk]; }
    float inv = 1.0f / den;

    float oacc[32];
    #pragma unroll
    for (int d = 0; d < 32; d++) oacc[d] = 0.f;
    #pragma unroll
    for (int kk = 0; kk < 16; kk++) {
        float p = lg[kk] * inv;
        #pragma unroll
        for (int d = 0; d < 32; d++) oacc[d] = fmaf(p, vs[h][kk][d], oacc[d]);
    }
    unsigned short* op = aw + g * 192 + h * 32;
    #pragma unroll
    for (int d = 0; d < 32; d++) op[d] = f2bf(oacc[d]);
}

// ---- Depthwise 5x5 conv + GELU + residual, one image; register sliding window ----
// Block: 64 ch x (8x8 spatial). Thread: 1 ch x 2 cols x 8 rows.
__global__ __launch_bounds__(256) void dwconv_kernel(
    const unsigned short* __restrict__ h1,
    const float* __restrict__ dwk, const float* __restrict__ dwb,
    unsigned short* __restrict__ hout)
{
    __shared__ float tile[12][12][64];
    int bx = blockIdx.x;
    int chb = bx % 12; int t = bx / 12;
    int tw = t % 32; int th = t / 32;
    const int tid = threadIdx.x;
    const int chbase = chb * 64;
    const int ch = tid & 63;
    const int cp = tid >> 6;          // 0..3 -> columns 2cp, 2cp+1
    const int c0 = cp * 2;

    // per-thread weights + bias in registers (tiny, L2-resident)
    float w[25];
    #pragma unroll
    for (int tap = 0; tap < 25; tap++)
        w[tap] = dwk[(size_t)(chbase + ch) * 25 + tap];
    const float bias = dwb[chbase + ch];

    // stage 12x12x64 input tile (zero-padded at image borders)
    const int lane4 = tid & 15;
    const int pg = tid >> 4;
    for (int p = pg; p < 144; p += 16) {
        int pr = p / 12, pc = p - pr * 12;
        int r = th * 8 - 2 + pr, c = tw * 8 - 2 + pc;
        float f0 = 0.f, f1 = 0.f, f2 = 0.f, f3 = 0.f;
        if (r >= 0 && r < 256 && c >= 0 && c < 256) {
            const unsigned short* sp = h1 + (((size_t)r * 256 + c) * HID + chbase + lane4 * 4);
            ushort4 u = *(const ushort4*)sp;
            f0 = bf2f(u.x); f1 = bf2f(u.y); f2 = bf2f(u.z); f3 = bf2f(u.w);
        }
        tile[pr][pc][lane4 * 4 + 0] = f0;
        tile[pr][pc][lane4 * 4 + 1] = f1;
        tile[pr][pc][lane4 * 4 + 2] = f2;
        tile[pr][pc][lane4 * 4 + 3] = f3;
    }
    __syncthreads();

    // sliding 5x6 register window down 8 output rows
    float win[5][6];
    #pragma unroll
    for (int rr = 0; rr < 4; rr++)
        #pragma unroll
        for (int cc = 0; cc < 6; cc++)
            win[rr][cc] = tile[rr][c0 + cc][ch];

    #pragma unroll
    for (int r0 = 0; r0 < 8; r0++) {
        #pragma unroll
        for (int cc = 0; cc < 6; cc++)
            win[(r0 + 4) % 5][cc] = tile[r0 + 4][c0 + cc][ch];
        float s0 = bias, s1 = bias;
        #pragma unroll
        for (int kr = 0; kr < 5; kr++) {
            int ri = (r0 + kr) % 5;
            #pragma unroll
            for (int kc = 0; kc < 5; kc++) {
                float wt = w[kr * 5 + kc];
                s0 = fmaf(win[ri][kc],     wt, s0);
                s1 = fmaf(win[ri][kc + 1], wt, s1);
            }
        }
        float v0 = win[(r0 + 2) % 5][2] + gelu_f(s0);
        float v1 = win[(r0 + 2) % 5][3] + gelu_f(s1);
        size_t tok = (size_t)(th * 8 + r0) * 256 + tw * 8 + c0;
        hout[tok * HID + chbase + ch]         = f2bf(v0);
        hout[(tok + 1) * HID + chbase + ch]   = f2bf(v1);
    }
}

// ---------------- launch ----------------
extern "C" void kernel_launch(void* const* d_in, const int* in_sizes, int n_in,
                              void* d_out, int out_size, void* d_ws, size_t ws_size,
                              hipStream_t stream) {
    const float* x    = (const float*)d_in[0];
    const float* g1   = (const float*)d_in[1];
    const float* be1  = (const float*)d_in[2];
    const float* wq   = (const float*)d_in[3];
    const float* bq   = (const float*)d_in[4];
    const float* wkv  = (const float*)d_in[5];
    const float* bkv  = (const float*)d_in[6];
    const float* btab = (const float*)d_in[7];
    const float* wproj= (const float*)d_in[8];
    const float* bproj= (const float*)d_in[9];
    const float* g2   = (const float*)d_in[10];
    const float* be2  = (const float*)d_in[11];
    const float* w1f  = (const float*)d_in[12];
    const float* b1f  = (const float*)d_in[13];
    const float* dwk  = (const float*)d_in[14];
    const float* dwb  = (const float*)d_in[15];
    const float* w2f  = (const float*)d_in[16];
    const float* b2f  = (const float*)d_in[17];
    float* out = (float*)d_out;

    // workspace layout (bytes), peak ~327.9 MB
    char* ws = (char*)d_ws;
    unsigned short* xnb  = (unsigned short*)(ws);              // xn -> aw (bf16)
    unsigned short* qb   = (unsigned short*)(ws + 50331648);   // q  -> xn2 (bf16)
    unsigned short* kvb  = (unsigned short*)(ws + 100663296);  // kv (bf16)
    unsigned short* h1b  = (unsigned short*)(ws + 125829120);  // h1, one image (bf16)
    unsigned short* hhb  = (unsigned short*)(ws + 226492416);  // h,  one image (bf16)
    unsigned short* qkvT = (unsigned short*)(ws + 327155712);  // [288][192]
    unsigned short* projT= (unsigned short*)(ws + 327266304);  // [192][192]
    unsigned short* w1T  = (unsigned short*)(ws + 327340032);  // [768][192]
    unsigned short* w2T  = (unsigned short*)(ws + 327634944);  // [192][768]

    // 0) weight transpose+cast
    wconv_kernel<<<576, 256, 0, stream>>>(wq, wkv, wproj, w1f, w2f,
                                          qkvT, projT, w1T, w2T);
    // 1) LN1 -> xnb
    ln_kernel<<<NTOK / 4, 256, 0, stream>>>(x, g1, be1, xnb);
    // 2) QKV projection -> qb, kvb
    mgemm_kernel<0><<<dim3(5, NTOK / 128), 256, 0, stream>>>(
        xnb, qkvT, bq, bkv, nullptr, qb, kvb, 192, 288);
    // 3) attention -> aw (token-major), overlays xnb
    attn_kernel<<<2048, 384, 0, stream>>>(qb, kvb, btab, xnb);
    // 4) proj + residual -> xattn lives in d_out
    mgemm_kernel<1><<<dim3(3, NTOK / 128), 256, 0, stream>>>(
        xnb, projT, bproj, nullptr, x, out, nullptr, 192, 192);
    // 5) LN2 -> xn2b (overlays qb)
    ln_kernel<<<NTOK / 4, 256, 0, stream>>>(out, g2, be2, qb);
    // 6-8) ConvFFN per batch image; FC2 accumulates into d_out
    for (int half = 0; half < 2; half++) {
        const unsigned short* xn2h = qb + (size_t)half * NTOKH * CD;
        float* outh = out + (size_t)half * NTOKH * CD;
        mgemm_kernel<2><<<dim3(12, NTOKH / 128), 256, 0, stream>>>(
            xn2h, w1T, b1f, nullptr, nullptr, h1b, nullptr, 192, 768);
        dwconv_kernel<<<12 * 32 * 32, 256, 0, stream>>>(h1b, dwk, dwb, hhb);
        mgemm_kernel<3><<<dim3(3, NTOKH / 128), 256, 0, stream>>>(
            hhb, w2T, b2f, nullptr, nullptr, outh, nullptr, 768, 192);
    }
}